// Round 4
// baseline (2748.552 us; speedup 1.0000x reference)
//
#include <hip/hip_runtime.h>
#include <stdint.h>

#define T_SEQ 2048
#define NH 16
#define HD 64
#define DM 1024
#define BB 4
#define MROWS (BB * T_SEQ)   // 8192

typedef __attribute__((ext_vector_type(8))) __bf16 bf16x8;
typedef __attribute__((ext_vector_type(8))) unsigned short u16x8;
typedef __attribute__((ext_vector_type(4))) unsigned int u32x4;
typedef __attribute__((ext_vector_type(4))) float f32x4;

__device__ __forceinline__ unsigned short f2bf(float f) {
  unsigned int x = __float_as_uint(f);
  x = (x + 0x7fffu + ((x >> 16) & 1u)) >> 16;  // RNE
  return (unsigned short)x;
}

__device__ __forceinline__ void cvt8(u16x8 u, float* f) {
  u32x4 w = __builtin_bit_cast(u32x4, u);
#pragma unroll
  for (int i = 0; i < 4; ++i) {
    unsigned int x = w[i];
    f[2 * i]     = __uint_as_float(x << 16);
    f[2 * i + 1] = __uint_as_float(x & 0xffff0000u);
  }
}

__device__ __forceinline__ bf16x8 ld8_f32(const float* __restrict__ p) {
  f32x4 a = *(const f32x4*)p;
  f32x4 b = *(const f32x4*)(p + 4);
  u16x8 u;
#pragma unroll
  for (int i = 0; i < 4; ++i) {
    u[i]     = f2bf(a[i]);
    u[i + 4] = f2bf(b[i]);
  }
  return __builtin_bit_cast(bf16x8, u);
}

__device__ __forceinline__ bf16x8 ld8_bf(const unsigned short* __restrict__ p) {
  return __builtin_bit_cast(bf16x8, *(const u16x8*)p);
}

// ---------------------------------------------------------------------------
// QKV projection: Y[M,N](bf16) = X[M,K](f32) @ W[N,K](f32)^T, MFMA fp32-acc.
// Per-wave 32x32 tile = 2x2 mfma_f32_16x16x32_bf16. Block = 4 waves -> 64x64.
// A frag: row = lane&15, k = (lane>>4)*8 + j.  C/D: col=lane&15, row=(lane>>4)*4+r.
// (Layout empirically validated: R2 MFMA == R3 reference-by-construction GEMM.)
// ---------------------------------------------------------------------------
__global__ __launch_bounds__(256) void gemm_qkv(
    const float* __restrict__ X, const float* __restrict__ W,
    unsigned short* __restrict__ Y, int M, int N, int K) {
  const int lane = threadIdx.x & 63;
  const int wave = threadIdx.x >> 6;
  const int m0 = blockIdx.y * 64 + (wave >> 1) * 32;
  const int n0 = blockIdx.x * 64 + (wave & 1) * 32;
  const int fr = lane & 15;
  const int kq = (lane >> 4) * 8;

  const float* pa0 = X + (size_t)(m0 + fr) * K + kq;
  const float* pa1 = pa0 + (size_t)16 * K;
  const float* pb0 = W + (size_t)(n0 + fr) * K + kq;
  const float* pb1 = pb0 + (size_t)16 * K;

  f32x4 acc00 = {0.f, 0.f, 0.f, 0.f};
  f32x4 acc01 = acc00, acc10 = acc00, acc11 = acc00;

  for (int k = 0; k < K; k += 32) {
    bf16x8 a0 = ld8_f32(pa0 + k);
    bf16x8 a1 = ld8_f32(pa1 + k);
    bf16x8 b0 = ld8_f32(pb0 + k);
    bf16x8 b1 = ld8_f32(pb1 + k);
    acc00 = __builtin_amdgcn_mfma_f32_16x16x32_bf16(a0, b0, acc00, 0, 0, 0);
    acc01 = __builtin_amdgcn_mfma_f32_16x16x32_bf16(a0, b1, acc01, 0, 0, 0);
    acc10 = __builtin_amdgcn_mfma_f32_16x16x32_bf16(a1, b0, acc10, 0, 0, 0);
    acc11 = __builtin_amdgcn_mfma_f32_16x16x32_bf16(a1, b1, acc11, 0, 0, 0);
  }

  const int orow = (lane >> 4) * 4;
  const int ocol = lane & 15;
#pragma unroll
  for (int r = 0; r < 4; ++r) {
    Y[(size_t)(m0 + orow + r) * N + (n0 + ocol)]           = f2bf(acc00[r]);
    Y[(size_t)(m0 + orow + r) * N + (n0 + 16 + ocol)]      = f2bf(acc01[r]);
    Y[(size_t)(m0 + 16 + orow + r) * N + (n0 + ocol)]      = f2bf(acc10[r]);
    Y[(size_t)(m0 + 16 + orow + r) * N + (n0 + 16 + ocol)] = f2bf(acc11[r]);
  }
}

// Final projection: Y[M,N](f32) = X[M,K](bf16) @ W[N,K](f32)^T.
__global__ __launch_bounds__(256) void gemm_out(
    const unsigned short* __restrict__ X, const float* __restrict__ W,
    float* __restrict__ Y, int M, int N, int K) {
  const int lane = threadIdx.x & 63;
  const int wave = threadIdx.x >> 6;
  const int m0 = blockIdx.y * 64 + (wave >> 1) * 32;
  const int n0 = blockIdx.x * 64 + (wave & 1) * 32;
  const int fr = lane & 15;
  const int kq = (lane >> 4) * 8;

  const unsigned short* pa0 = X + (size_t)(m0 + fr) * K + kq;
  const unsigned short* pa1 = pa0 + (size_t)16 * K;
  const float* pb0 = W + (size_t)(n0 + fr) * K + kq;
  const float* pb1 = pb0 + (size_t)16 * K;

  f32x4 acc00 = {0.f, 0.f, 0.f, 0.f};
  f32x4 acc01 = acc00, acc10 = acc00, acc11 = acc00;

  for (int k = 0; k < K; k += 32) {
    bf16x8 a0 = ld8_bf(pa0 + k);
    bf16x8 a1 = ld8_bf(pa1 + k);
    bf16x8 b0 = ld8_f32(pb0 + k);
    bf16x8 b1 = ld8_f32(pb1 + k);
    acc00 = __builtin_amdgcn_mfma_f32_16x16x32_bf16(a0, b0, acc00, 0, 0, 0);
    acc01 = __builtin_amdgcn_mfma_f32_16x16x32_bf16(a0, b1, acc01, 0, 0, 0);
    acc10 = __builtin_amdgcn_mfma_f32_16x16x32_bf16(a1, b0, acc10, 0, 0, 0);
    acc11 = __builtin_amdgcn_mfma_f32_16x16x32_bf16(a1, b1, acc11, 0, 0, 0);
  }

  const int orow = (lane >> 4) * 4;
  const int ocol = lane & 15;
#pragma unroll
  for (int r = 0; r < 4; ++r) {
    Y[(size_t)(m0 + orow + r) * N + (n0 + ocol)]           = acc00[r];
    Y[(size_t)(m0 + orow + r) * N + (n0 + 16 + ocol)]      = acc01[r];
    Y[(size_t)(m0 + 16 + orow + r) * N + (n0 + ocol)]      = acc10[r];
    Y[(size_t)(m0 + 16 + orow + r) * N + (n0 + 16 + ocol)] = acc11[r];
  }
}

// ---------------------------------------------------------------------------
// Causal attention, one thread per query row, online softmax (thread-local).
// Q/K/V/O stored as [B*T, DM] bf16 rows; head h occupies cols [h*64, h*64+64).
// ---------------------------------------------------------------------------
#define TKEY 64
#define LDSTR 72  // +8 bf16 pad

__global__ __launch_bounds__(256, 2) void attn_causal(
    const unsigned short* __restrict__ Qw,
    const unsigned short* __restrict__ Kw,
    const unsigned short* __restrict__ Vw,
    unsigned short* __restrict__ Ow) {
  __shared__ unsigned short k_lds[TKEY][LDSTR];
  __shared__ unsigned short v_lds[TKEY][LDSTR];
  const int tid = threadIdx.x;
  const int b = blockIdx.z, h = blockIdx.y;
  const int q_base = blockIdx.x * 256;
  const int qi = q_base + tid;
  const size_t rowbase = (size_t)(b * T_SEQ) * DM + h * HD;
  const size_t qoff = rowbase + (size_t)qi * DM;

  float q[HD];
#pragma unroll
  for (int c = 0; c < 8; ++c) {
    u16x8 u = *(const u16x8*)(Qw + qoff + c * 8);
    cvt8(u, &q[c * 8]);
  }
  float acc[HD];
#pragma unroll
  for (int d = 0; d < HD; ++d) acc[d] = 0.f;
  float m_run = -3.0e38f, l_run = 0.f;

  const int n_tiles = blockIdx.x * 4 + 4;  // keys up to q_base+255 inclusive
  const int sr = tid >> 2;
  const int sc = (tid & 3) * 16;

  for (int tt = 0; tt < n_tiles; ++tt) {
    const int kb = tt * TKEY;
    __syncthreads();
    {
      const size_t g = rowbase + (size_t)(kb + sr) * DM + sc;
      u16x8 k0 = *(const u16x8*)(Kw + g);
      u16x8 k1 = *(const u16x8*)(Kw + g + 8);
      u16x8 v0 = *(const u16x8*)(Vw + g);
      u16x8 v1 = *(const u16x8*)(Vw + g + 8);
      *(u16x8*)&k_lds[sr][sc]     = k0;
      *(u16x8*)&k_lds[sr][sc + 8] = k1;
      *(u16x8*)&v_lds[sr][sc]     = v0;
      *(u16x8*)&v_lds[sr][sc + 8] = v1;
    }
    __syncthreads();

    for (int j0 = 0; j0 < TKEY; j0 += 8) {
      float s[8];
#pragma unroll
      for (int jj = 0; jj < 8; ++jj) {
        const u16x8* kr = (const u16x8*)&k_lds[j0 + jj][0];
        float acc_s = 0.f;
#pragma unroll
        for (int c8 = 0; c8 < 8; ++c8) {
          float kf[8];
          cvt8(kr[c8], kf);
#pragma unroll
          for (int i = 0; i < 8; ++i) acc_s += q[c8 * 8 + i] * kf[i];
        }
        s[jj] = (kb + j0 + jj <= qi) ? acc_s * 0.125f : -3.0e38f;
      }
      float mc = s[0];
#pragma unroll
      for (int jj = 1; jj < 8; ++jj) mc = fmaxf(mc, s[jj]);
      if (mc < -1.0e37f) continue;  // whole chunk masked for this thread
      const float m_new = fmaxf(m_run, mc);
      const float alpha = __expf(m_run - m_new);
      float p[8], psum = 0.f;
#pragma unroll
      for (int jj = 0; jj < 8; ++jj) {
        p[jj] = __expf(s[jj] - m_new);  // masked -> underflows to 0
        psum += p[jj];
      }
      l_run = l_run * alpha + psum;
      m_run = m_new;
#pragma unroll
      for (int c8 = 0; c8 < 8; ++c8) {
        float a[8];
#pragma unroll
        for (int i = 0; i < 8; ++i) a[i] = acc[c8 * 8 + i] * alpha;
#pragma unroll
        for (int jj = 0; jj < 8; ++jj) {
          float vf[8];
          cvt8(((const u16x8*)&v_lds[j0 + jj][0])[c8], vf);
#pragma unroll
          for (int i = 0; i < 8; ++i) a[i] += p[jj] * vf[i];
        }
#pragma unroll
        for (int i = 0; i < 8; ++i) acc[c8 * 8 + i] = a[i];
      }
    }
  }

  const float inv_l = 1.0f / l_run;  // l_run >= 1 (self-key always valid)
#pragma unroll
  for (int c = 0; c < 8; ++c) {
    u16x8 o;
#pragma unroll
    for (int i = 0; i < 8; ++i) o[i] = f2bf(acc[c * 8 + i] * inv_l);
    *(u16x8*)(Ow + qoff + c * 8) = o;
  }
}

extern "C" void kernel_launch(void* const* d_in, const int* in_sizes, int n_in,
                              void* d_out, int out_size, void* d_ws, size_t ws_size,
                              hipStream_t stream) {
  const float* x_q  = (const float*)d_in[0];  // fp32 [4,2048,1024]
  const float* x_kv = (const float*)d_in[1];  // fp32
  const float* Wq   = (const float*)d_in[2];  // fp32 [1024,1024]
  const float* Wk   = (const float*)d_in[3];
  const float* Wv   = (const float*)d_in[4];
  const float* Wo   = (const float*)d_in[5];
  float* out = (float*)d_out;                 // fp32 [4,2048,1024]

  unsigned short* qb = (unsigned short*)d_ws;     // [8192,1024] bf16
  unsigned short* kb = qb + (size_t)MROWS * DM;
  unsigned short* vb = kb + (size_t)MROWS * DM;
  unsigned short* ab = vb + (size_t)MROWS * DM;   // attn output rows

  dim3 gg(DM / 64, MROWS / 64);  // (16, 128)
  gemm_qkv<<<gg, 256, 0, stream>>>(x_q,  Wq, qb, MROWS, DM, DM);
  gemm_qkv<<<gg, 256, 0, stream>>>(x_kv, Wk, kb, MROWS, DM, DM);
  gemm_qkv<<<gg, 256, 0, stream>>>(x_kv, Wv, vb, MROWS, DM, DM);
  attn_causal<<<dim3(T_SEQ / 256, NH, BB), 256, 0, stream>>>(qb, kb, vb, ab);
  gemm_out<<<gg, 256, 0, stream>>>(ab, Wo, out, MROWS, DM, DM);
}

// Round 5
// 1212.291 us; speedup vs baseline: 2.2672x; 2.2672x over previous
//
#include <hip/hip_runtime.h>
#include <stdint.h>

#define T_SEQ 2048
#define NH 16
#define HD 64
#define DM 1024
#define BB 4
#define MROWS (BB * T_SEQ)   // 8192

typedef __attribute__((ext_vector_type(8))) __bf16 bf16x8;
typedef __attribute__((ext_vector_type(8))) unsigned short u16x8;
typedef __attribute__((ext_vector_type(4))) float f32x4;

__device__ __forceinline__ unsigned short f2bf(float f) {
  unsigned int x = __float_as_uint(f);
  x = (x + 0x7fffu + ((x >> 16) & 1u)) >> 16;  // RNE
  return (unsigned short)x;
}

__device__ __forceinline__ bf16x8 ld8_f32(const float* __restrict__ p) {
  f32x4 a = *(const f32x4*)p;
  f32x4 b = *(const f32x4*)(p + 4);
  u16x8 u;
#pragma unroll
  for (int i = 0; i < 4; ++i) {
    u[i]     = f2bf(a[i]);
    u[i + 4] = f2bf(b[i]);
  }
  return __builtin_bit_cast(bf16x8, u);
}

__device__ __forceinline__ bf16x8 ld8_bf(const unsigned short* p) {
  return __builtin_bit_cast(bf16x8, *(const u16x8*)p);
}

// ---------------------------------------------------------------------------
// QKV projection: Y[M,N](bf16) = X[M,K](f32) @ W[N,K](f32)^T, MFMA fp32-acc.
// Layout empirically validated (R2 MFMA == R3 scalar-reference GEMM, R4 pass).
// ---------------------------------------------------------------------------
__global__ __launch_bounds__(256) void gemm_qkv(
    const float* __restrict__ X, const float* __restrict__ W,
    unsigned short* __restrict__ Y, int M, int N, int K) {
  const int lane = threadIdx.x & 63;
  const int wave = threadIdx.x >> 6;
  const int m0 = blockIdx.y * 64 + (wave >> 1) * 32;
  const int n0 = blockIdx.x * 64 + (wave & 1) * 32;
  const int fr = lane & 15;
  const int kq = (lane >> 4) * 8;

  const float* pa0 = X + (size_t)(m0 + fr) * K + kq;
  const float* pa1 = pa0 + (size_t)16 * K;
  const float* pb0 = W + (size_t)(n0 + fr) * K + kq;
  const float* pb1 = pb0 + (size_t)16 * K;

  f32x4 acc00 = {0.f, 0.f, 0.f, 0.f};
  f32x4 acc01 = acc00, acc10 = acc00, acc11 = acc00;

  for (int k = 0; k < K; k += 32) {
    bf16x8 a0 = ld8_f32(pa0 + k);
    bf16x8 a1 = ld8_f32(pa1 + k);
    bf16x8 b0 = ld8_f32(pb0 + k);
    bf16x8 b1 = ld8_f32(pb1 + k);
    acc00 = __builtin_amdgcn_mfma_f32_16x16x32_bf16(a0, b0, acc00, 0, 0, 0);
    acc01 = __builtin_amdgcn_mfma_f32_16x16x32_bf16(a0, b1, acc01, 0, 0, 0);
    acc10 = __builtin_amdgcn_mfma_f32_16x16x32_bf16(a1, b0, acc10, 0, 0, 0);
    acc11 = __builtin_amdgcn_mfma_f32_16x16x32_bf16(a1, b1, acc11, 0, 0, 0);
  }

  const int orow = (lane >> 4) * 4;
  const int ocol = lane & 15;
#pragma unroll
  for (int r = 0; r < 4; ++r) {
    Y[(size_t)(m0 + orow + r) * N + (n0 + ocol)]           = f2bf(acc00[r]);
    Y[(size_t)(m0 + orow + r) * N + (n0 + 16 + ocol)]      = f2bf(acc01[r]);
    Y[(size_t)(m0 + 16 + orow + r) * N + (n0 + ocol)]      = f2bf(acc10[r]);
    Y[(size_t)(m0 + 16 + orow + r) * N + (n0 + 16 + ocol)] = f2bf(acc11[r]);
  }
}

// Final projection: Y[M,N](f32) = X[M,K](bf16) @ W[N,K](f32)^T.
__global__ __launch_bounds__(256) void gemm_out(
    const unsigned short* __restrict__ X, const float* __restrict__ W,
    float* __restrict__ Y, int M, int N, int K) {
  const int lane = threadIdx.x & 63;
  const int wave = threadIdx.x >> 6;
  const int m0 = blockIdx.y * 64 + (wave >> 1) * 32;
  const int n0 = blockIdx.x * 64 + (wave & 1) * 32;
  const int fr = lane & 15;
  const int kq = (lane >> 4) * 8;

  const unsigned short* pa0 = X + (size_t)(m0 + fr) * K + kq;
  const unsigned short* pa1 = pa0 + (size_t)16 * K;
  const float* pb0 = W + (size_t)(n0 + fr) * K + kq;
  const float* pb1 = pb0 + (size_t)16 * K;

  f32x4 acc00 = {0.f, 0.f, 0.f, 0.f};
  f32x4 acc01 = acc00, acc10 = acc00, acc11 = acc00;

  for (int k = 0; k < K; k += 32) {
    bf16x8 a0 = ld8_bf(pa0 + k);
    bf16x8 a1 = ld8_bf(pa1 + k);
    bf16x8 b0 = ld8_f32(pb0 + k);
    bf16x8 b1 = ld8_f32(pb1 + k);
    acc00 = __builtin_amdgcn_mfma_f32_16x16x32_bf16(a0, b0, acc00, 0, 0, 0);
    acc01 = __builtin_amdgcn_mfma_f32_16x16x32_bf16(a0, b1, acc01, 0, 0, 0);
    acc10 = __builtin_amdgcn_mfma_f32_16x16x32_bf16(a1, b0, acc10, 0, 0, 0);
    acc11 = __builtin_amdgcn_mfma_f32_16x16x32_bf16(a1, b1, acc11, 0, 0, 0);
  }

  const int orow = (lane >> 4) * 4;
  const int ocol = lane & 15;
#pragma unroll
  for (int r = 0; r < 4; ++r) {
    Y[(size_t)(m0 + orow + r) * N + (n0 + ocol)]           = acc00[r];
    Y[(size_t)(m0 + orow + r) * N + (n0 + 16 + ocol)]      = acc01[r];
    Y[(size_t)(m0 + 16 + orow + r) * N + (n0 + ocol)]      = acc10[r];
    Y[(size_t)(m0 + 16 + orow + r) * N + (n0 + 16 + ocol)] = acc11[r];
  }
}

// ---------------------------------------------------------------------------
// MFMA flash attention (causal). Block = 64 q-rows of one (b,h); 4 waves,
// each wave owns 16 q-rows. Keys iterated in 64-wide tiles staged in LDS:
// K row-major, V transposed (Vt[d][k]) so QK^T and PV both use the validated
// mfma_f32_16x16x32_bf16 "A[m][k] x B[n][k]" pattern. P converts C-layout ->
// A-layout via a wave-private LDS slab. Stride 72 (=64+8) rotates banks.
// ---------------------------------------------------------------------------
#define KSTR 72

__global__ __launch_bounds__(256) void attn_flash(
    const unsigned short* __restrict__ Qw,
    const unsigned short* __restrict__ Kw,
    const unsigned short* __restrict__ Vw,
    unsigned short* __restrict__ Ow) {
  __shared__ unsigned short k_lds[64][KSTR];
  __shared__ unsigned short vt_lds[HD][KSTR];
  __shared__ unsigned short p_lds[4][16][KSTR];

  const int tid = threadIdx.x;
  const int lane = tid & 63;
  const int wave = tid >> 6;
  const int b = blockIdx.z, h = blockIdx.y, qt = blockIdx.x;
  const int qb0 = qt * 64;
  const size_t bbase = (size_t)b * T_SEQ * DM + (size_t)h * HD;

  // Q fragments for this wave's 16 rows (resident all kernel).
  // A-frag: row = lane&15, k(d) = (lane>>4)*8 + j (+32 for second frag).
  const int qrow = qb0 + wave * 16 + (lane & 15);
  const unsigned short* qp = Qw + bbase + (size_t)qrow * DM + ((lane >> 4) * 8);
  const bf16x8 qf0 = ld8_bf(qp);
  const bf16x8 qf1 = ld8_bf(qp + 32);

  f32x4 o[4];
#pragma unroll
  for (int d = 0; d < 4; ++d) o[d] = (f32x4){0.f, 0.f, 0.f, 0.f};
  float m_r[4] = {-3.0e38f, -3.0e38f, -3.0e38f, -3.0e38f};
  float l_r[4] = {0.f, 0.f, 0.f, 0.f};

  const int srow = tid >> 2;        // staging: key row 0..63
  const int scol = (tid & 3) * 16;  // staging: d-offset 0/16/32/48
  const int ntiles = qt + 1;

  for (int t = 0; t < ntiles; ++t) {
    const int kb0 = t * 64;
    __syncthreads();
    {
      const unsigned short* kp = Kw + bbase + (size_t)(kb0 + srow) * DM + scol;
      u16x8 ka = *(const u16x8*)kp;
      u16x8 kc = *(const u16x8*)(kp + 8);
      const unsigned short* vp = Vw + bbase + (size_t)(kb0 + srow) * DM + scol;
      u16x8 va = *(const u16x8*)vp;
      u16x8 vc = *(const u16x8*)(vp + 8);
      *(u16x8*)&k_lds[srow][scol]     = ka;
      *(u16x8*)&k_lds[srow][scol + 8] = kc;
#pragma unroll
      for (int j = 0; j < 8; ++j) vt_lds[scol + j][srow]     = va[j];
#pragma unroll
      for (int j = 0; j < 8; ++j) vt_lds[scol + 8 + j][srow] = vc[j];
    }
    __syncthreads();

    // ---- QK^T: 4 score frags (16q x 16k each) ----
    f32x4 s[4];
#pragma unroll
    for (int f = 0; f < 4; ++f) {
      const unsigned short* kr = &k_lds[f * 16 + (lane & 15)][(lane >> 4) * 8];
      f32x4 a = {0.f, 0.f, 0.f, 0.f};
      a = __builtin_amdgcn_mfma_f32_16x16x32_bf16(qf0, ld8_bf(kr), a, 0, 0, 0);
      a = __builtin_amdgcn_mfma_f32_16x16x32_bf16(qf1, ld8_bf(kr + 32), a, 0, 0, 0);
      s[f] = a;
    }
    // scale + causal mask (only the diagonal tile needs masking)
    if (t == ntiles - 1) {
      const int qg = qb0 + wave * 16 + (lane >> 4) * 4;  // + r
#pragma unroll
      for (int f = 0; f < 4; ++f) {
        const int kg = kb0 + f * 16 + (lane & 15);
#pragma unroll
        for (int r = 0; r < 4; ++r)
          s[f][r] = (kg <= qg + r) ? s[f][r] * 0.125f : -3.0e38f;
      }
    } else {
#pragma unroll
      for (int f = 0; f < 4; ++f)
#pragma unroll
        for (int r = 0; r < 4; ++r) s[f][r] *= 0.125f;
    }

    // ---- online softmax over this tile's 64 cols ----
    float alpha[4];
#pragma unroll
    for (int r = 0; r < 4; ++r) {
      float v = fmaxf(fmaxf(s[0][r], s[1][r]), fmaxf(s[2][r], s[3][r]));
      v = fmaxf(v, __shfl_xor(v, 1, 64));
      v = fmaxf(v, __shfl_xor(v, 2, 64));
      v = fmaxf(v, __shfl_xor(v, 4, 64));
      v = fmaxf(v, __shfl_xor(v, 8, 64));
      const float m_new = fmaxf(m_r[r], v);
      alpha[r] = __expf(m_r[r] - m_new);
      m_r[r] = m_new;
    }
    float p[4][4];
    float psum[4] = {0.f, 0.f, 0.f, 0.f};
#pragma unroll
    for (int f = 0; f < 4; ++f)
#pragma unroll
      for (int r = 0; r < 4; ++r) {
        const float e = __expf(s[f][r] - m_r[r]);  // masked -> 0
        p[f][r] = e;
        psum[r] += e;
      }
#pragma unroll
    for (int r = 0; r < 4; ++r) {
      float v = psum[r];
      v += __shfl_xor(v, 1, 64);
      v += __shfl_xor(v, 2, 64);
      v += __shfl_xor(v, 4, 64);
      v += __shfl_xor(v, 8, 64);
      l_r[r] = l_r[r] * alpha[r] + v;
    }

    // ---- P: C-layout -> A-layout via wave-private LDS ----
    {
      const int prow = (lane >> 4) * 4;
      const int pcol = lane & 15;
#pragma unroll
      for (int f = 0; f < 4; ++f)
#pragma unroll
        for (int r = 0; r < 4; ++r)
          p_lds[wave][prow + r][f * 16 + pcol] = f2bf(p[f][r]);
    }
    __threadfence_block();  // lgkmcnt drain: P writes visible to wave's reads

    // rescale O by alpha
#pragma unroll
    for (int d = 0; d < 4; ++d)
#pragma unroll
      for (int r = 0; r < 4; ++r) o[d][r] *= alpha[r];

    // ---- PV: O[q][d] += P[q][k] * Vt[d][k] ----
    const unsigned short* pw = &p_lds[wave][lane & 15][(lane >> 4) * 8];
    const bf16x8 pf0 = ld8_bf(pw);
    const bf16x8 pf1 = ld8_bf(pw + 32);
#pragma unroll
    for (int d = 0; d < 4; ++d) {
      const unsigned short* vr = &vt_lds[d * 16 + (lane & 15)][(lane >> 4) * 8];
      o[d] = __builtin_amdgcn_mfma_f32_16x16x32_bf16(pf0, ld8_bf(vr), o[d], 0, 0, 0);
      o[d] = __builtin_amdgcn_mfma_f32_16x16x32_bf16(pf1, ld8_bf(vr + 32), o[d], 0, 0, 0);
    }
  }

  // ---- epilogue: O / l, C-layout scatter to bf16 rows ----
  const int qg = qb0 + wave * 16 + (lane >> 4) * 4;
  const int oc = lane & 15;
#pragma unroll
  for (int r = 0; r < 4; ++r) {
    const float inv = 1.0f / l_r[r];
    unsigned short* orow = Ow + bbase + (size_t)(qg + r) * DM;
#pragma unroll
    for (int d = 0; d < 4; ++d) orow[d * 16 + oc] = f2bf(o[d][r] * inv);
  }
}

extern "C" void kernel_launch(void* const* d_in, const int* in_sizes, int n_in,
                              void* d_out, int out_size, void* d_ws, size_t ws_size,
                              hipStream_t stream) {
  const float* x_q  = (const float*)d_in[0];  // fp32 [4,2048,1024]
  const float* x_kv = (const float*)d_in[1];
  const float* Wq   = (const float*)d_in[2];  // fp32 [1024,1024]
  const float* Wk   = (const float*)d_in[3];
  const float* Wv   = (const float*)d_in[4];
  const float* Wo   = (const float*)d_in[5];
  float* out = (float*)d_out;                 // fp32 [4,2048,1024]

  unsigned short* qb = (unsigned short*)d_ws;     // [8192,1024] bf16
  unsigned short* kb = qb + (size_t)MROWS * DM;
  unsigned short* vb = kb + (size_t)MROWS * DM;
  unsigned short* ab = vb + (size_t)MROWS * DM;   // attn output rows

  dim3 gg(DM / 64, MROWS / 64);  // (16, 128)
  gemm_qkv<<<gg, 256, 0, stream>>>(x_q,  Wq, qb, MROWS, DM, DM);
  gemm_qkv<<<gg, 256, 0, stream>>>(x_kv, Wk, kb, MROWS, DM, DM);
  gemm_qkv<<<gg, 256, 0, stream>>>(x_kv, Wv, vb, MROWS, DM, DM);
  attn_flash<<<dim3(T_SEQ / 64, NH, BB), 256, 0, stream>>>(qb, kb, vb, ab);
  gemm_out<<<gg, 256, 0, stream>>>(ab, Wo, out, MROWS, DM, DM);
}

// Round 6
// 514.001 us; speedup vs baseline: 5.3474x; 2.3585x over previous
//
#include <hip/hip_runtime.h>
#include <stdint.h>

#define T_SEQ 2048
#define NH 16
#define HD 64
#define DM 1024
#define BB 4
#define MROWS (BB * T_SEQ)   // 8192

typedef __attribute__((ext_vector_type(8))) __bf16 bf16x8;
typedef __attribute__((ext_vector_type(8))) unsigned short u16x8;
typedef __attribute__((ext_vector_type(4))) float f32x4;

__device__ __forceinline__ unsigned short f2bf(float f) {
  unsigned int x = __float_as_uint(f);
  x = (x + 0x7fffu + ((x >> 16) & 1u)) >> 16;  // RNE
  return (unsigned short)x;
}

__device__ __forceinline__ bf16x8 ld8_f32(const float* __restrict__ p) {
  f32x4 a = *(const f32x4*)p;
  f32x4 b = *(const f32x4*)(p + 4);
  u16x8 u;
#pragma unroll
  for (int i = 0; i < 4; ++i) {
    u[i]     = f2bf(a[i]);
    u[i + 4] = f2bf(b[i]);
  }
  return __builtin_bit_cast(bf16x8, u);
}

__device__ __forceinline__ bf16x8 ld8_bf(const unsigned short* p) {
  return __builtin_bit_cast(bf16x8, *(const u16x8*)p);
}

__device__ __forceinline__ void gload_lds16(const unsigned short* g,
                                            unsigned short* l) {
  __builtin_amdgcn_global_load_lds(
      (const __attribute__((address_space(1))) unsigned int*)g,
      (__attribute__((address_space(3))) unsigned int*)l, 16, 0, 0);
}

// ---------------------------------------------------------------------------
// fp32 -> bf16 elementwise (8 elems/thread). n must be a multiple of 8.
// ---------------------------------------------------------------------------
__global__ __launch_bounds__(256) void conv_f32_bf16(
    const float* __restrict__ src, unsigned short* __restrict__ dst, int n8) {
  const int i = blockIdx.x * 256 + threadIdx.x;
  if (i < n8)
    *(u16x8*)(dst + (size_t)i * 8) =
        __builtin_bit_cast(u16x8, ld8_f32(src + (size_t)i * 8));
}

// ---------------------------------------------------------------------------
// m97-style bf16 GEMM: C[M,N] = A[M,K] @ B[N,K]^T.
// 128x128 tile, BK=32, global_load_lds width=16, 16 MFMA / K-iter / wave.
// OutT = unsigned short (bf16 store) or float (f32 store).
// ---------------------------------------------------------------------------
template <typename OutT>
__global__ __launch_bounds__(256) void gemm128(
    const unsigned short* __restrict__ A, const unsigned short* __restrict__ B,
    OutT* __restrict__ C, int M, int N, int K) {
  __shared__ __align__(16) unsigned short As[128 * 32];
  __shared__ __align__(16) unsigned short Bs[128 * 32];

  const int t = threadIdx.x;
  const int lane = t & 63, wave = t >> 6;
  const int m0 = blockIdx.y * 128, n0 = blockIdx.x * 128;

  // staging: thread t covers row (t>>2), k-cols (t&3)*8 .. +8 (16 B)
  const int srow = t >> 2;
  const int scol = (t & 3) * 8;
  const unsigned short* ga0 = A + (size_t)(m0 + srow) * K + scol;
  const unsigned short* ga1 = A + (size_t)(m0 + 64 + srow) * K + scol;
  const unsigned short* gb0 = B + (size_t)(n0 + srow) * K + scol;
  const unsigned short* gb1 = B + (size_t)(n0 + 64 + srow) * K + scol;
  // wave-uniform LDS bases (HW scatters lane i to base + i*16)
  unsigned short* lA0 = &As[(wave * 16) * 32];
  unsigned short* lA1 = &As[(64 + wave * 16) * 32];
  unsigned short* lB0 = &Bs[(wave * 16) * 32];
  unsigned short* lB1 = &Bs[(64 + wave * 16) * 32];

  // compute: wave covers 64x64 of the 128x128 tile, 4x4 frags of 16x16
  const int mw = (wave >> 1) * 64, nw = (wave & 1) * 64;
  const int fr = lane & 15, fq = (lane >> 4) * 8;

  f32x4 acc[4][4];
#pragma unroll
  for (int i = 0; i < 4; ++i)
#pragma unroll
    for (int j = 0; j < 4; ++j) acc[i][j] = (f32x4){0.f, 0.f, 0.f, 0.f};

  for (int k0 = 0; k0 < K; k0 += 32) {
    __syncthreads();  // previous iteration's LDS reads complete
    gload_lds16(ga0 + k0, lA0);
    gload_lds16(ga1 + k0, lA1);
    gload_lds16(gb0 + k0, lB0);
    gload_lds16(gb1 + k0, lB1);
    __syncthreads();  // vmcnt(0) drain: DMA complete

    bf16x8 af[4], bfr[4];
#pragma unroll
    for (int i = 0; i < 4; ++i)
      af[i] = ld8_bf(&As[(mw + i * 16 + fr) * 32 + fq]);
#pragma unroll
    for (int j = 0; j < 4; ++j)
      bfr[j] = ld8_bf(&Bs[(nw + j * 16 + fr) * 32 + fq]);
#pragma unroll
    for (int i = 0; i < 4; ++i)
#pragma unroll
      for (int j = 0; j < 4; ++j)
        acc[i][j] = __builtin_amdgcn_mfma_f32_16x16x32_bf16(af[i], bfr[j],
                                                            acc[i][j], 0, 0, 0);
  }

  // epilogue: C/D layout col=lane&15, row=(lane>>4)*4+r (validated R2-R5)
  const int orow = (lane >> 4) * 4, ocol = lane & 15;
#pragma unroll
  for (int i = 0; i < 4; ++i)
#pragma unroll
    for (int j = 0; j < 4; ++j)
#pragma unroll
      for (int r = 0; r < 4; ++r) {
        const size_t idx =
            (size_t)(m0 + mw + i * 16 + orow + r) * N + (n0 + nw + j * 16 + ocol);
        if constexpr (sizeof(OutT) == 4)
          C[idx] = acc[i][j][r];
        else
          C[idx] = f2bf(acc[i][j][r]);
      }
}

// ---------------------------------------------------------------------------
// MFMA flash attention (causal), unchanged from R5 except Qw/Ow may alias
// (in-place O over Q: each block reads only its own Q rows into registers
// before writing them; cross-block slices are disjoint).
// ---------------------------------------------------------------------------
#define KSTR 72

__global__ __launch_bounds__(256) void attn_flash(
    const unsigned short* Qw,
    const unsigned short* __restrict__ Kw,
    const unsigned short* __restrict__ Vw,
    unsigned short* Ow) {
  __shared__ unsigned short k_lds[64][KSTR];
  __shared__ unsigned short vt_lds[HD][KSTR];
  __shared__ unsigned short p_lds[4][16][KSTR];

  const int tid = threadIdx.x;
  const int lane = tid & 63;
  const int wave = tid >> 6;
  const int b = blockIdx.z, h = blockIdx.y, qt = blockIdx.x;
  const int qb0 = qt * 64;
  const size_t bbase = (size_t)b * T_SEQ * DM + (size_t)h * HD;

  const int qrow = qb0 + wave * 16 + (lane & 15);
  const unsigned short* qp = Qw + bbase + (size_t)qrow * DM + ((lane >> 4) * 8);
  const bf16x8 qf0 = ld8_bf(qp);
  const bf16x8 qf1 = ld8_bf(qp + 32);

  f32x4 o[4];
#pragma unroll
  for (int d = 0; d < 4; ++d) o[d] = (f32x4){0.f, 0.f, 0.f, 0.f};
  float m_r[4] = {-3.0e38f, -3.0e38f, -3.0e38f, -3.0e38f};
  float l_r[4] = {0.f, 0.f, 0.f, 0.f};

  const int srow = tid >> 2;
  const int scol = (tid & 3) * 16;
  const int ntiles = qt + 1;

  for (int t = 0; t < ntiles; ++t) {
    const int kb0 = t * 64;
    __syncthreads();
    {
      const unsigned short* kp = Kw + bbase + (size_t)(kb0 + srow) * DM + scol;
      u16x8 ka = *(const u16x8*)kp;
      u16x8 kc = *(const u16x8*)(kp + 8);
      const unsigned short* vp = Vw + bbase + (size_t)(kb0 + srow) * DM + scol;
      u16x8 va = *(const u16x8*)vp;
      u16x8 vc = *(const u16x8*)(vp + 8);
      *(u16x8*)&k_lds[srow][scol]     = ka;
      *(u16x8*)&k_lds[srow][scol + 8] = kc;
#pragma unroll
      for (int j = 0; j < 8; ++j) vt_lds[scol + j][srow]     = va[j];
#pragma unroll
      for (int j = 0; j < 8; ++j) vt_lds[scol + 8 + j][srow] = vc[j];
    }
    __syncthreads();

    f32x4 s[4];
#pragma unroll
    for (int f = 0; f < 4; ++f) {
      const unsigned short* kr = &k_lds[f * 16 + (lane & 15)][(lane >> 4) * 8];
      f32x4 a = {0.f, 0.f, 0.f, 0.f};
      a = __builtin_amdgcn_mfma_f32_16x16x32_bf16(qf0, ld8_bf(kr), a, 0, 0, 0);
      a = __builtin_amdgcn_mfma_f32_16x16x32_bf16(qf1, ld8_bf(kr + 32), a, 0, 0, 0);
      s[f] = a;
    }
    if (t == ntiles - 1) {
      const int qg = qb0 + wave * 16 + (lane >> 4) * 4;
#pragma unroll
      for (int f = 0; f < 4; ++f) {
        const int kg = kb0 + f * 16 + (lane & 15);
#pragma unroll
        for (int r = 0; r < 4; ++r)
          s[f][r] = (kg <= qg + r) ? s[f][r] * 0.125f : -3.0e38f;
      }
    } else {
#pragma unroll
      for (int f = 0; f < 4; ++f)
#pragma unroll
        for (int r = 0; r < 4; ++r) s[f][r] *= 0.125f;
    }

    float alpha[4];
#pragma unroll
    for (int r = 0; r < 4; ++r) {
      float v = fmaxf(fmaxf(s[0][r], s[1][r]), fmaxf(s[2][r], s[3][r]));
      v = fmaxf(v, __shfl_xor(v, 1, 64));
      v = fmaxf(v, __shfl_xor(v, 2, 64));
      v = fmaxf(v, __shfl_xor(v, 4, 64));
      v = fmaxf(v, __shfl_xor(v, 8, 64));
      const float m_new = fmaxf(m_r[r], v);
      alpha[r] = __expf(m_r[r] - m_new);
      m_r[r] = m_new;
    }
    float p[4][4];
    float psum[4] = {0.f, 0.f, 0.f, 0.f};
#pragma unroll
    for (int f = 0; f < 4; ++f)
#pragma unroll
      for (int r = 0; r < 4; ++r) {
        const float e = __expf(s[f][r] - m_r[r]);
        p[f][r] = e;
        psum[r] += e;
      }
#pragma unroll
    for (int r = 0; r < 4; ++r) {
      float v = psum[r];
      v += __shfl_xor(v, 1, 64);
      v += __shfl_xor(v, 2, 64);
      v += __shfl_xor(v, 4, 64);
      v += __shfl_xor(v, 8, 64);
      l_r[r] = l_r[r] * alpha[r] + v;
    }

    {
      const int prow = (lane >> 4) * 4;
      const int pcol = lane & 15;
#pragma unroll
      for (int f = 0; f < 4; ++f)
#pragma unroll
        for (int r = 0; r < 4; ++r)
          p_lds[wave][prow + r][f * 16 + pcol] = f2bf(p[f][r]);
    }
    __threadfence_block();

#pragma unroll
    for (int d = 0; d < 4; ++d)
#pragma unroll
      for (int r = 0; r < 4; ++r) o[d][r] *= alpha[r];

    const unsigned short* pw = &p_lds[wave][lane & 15][(lane >> 4) * 8];
    const bf16x8 pf0 = ld8_bf(pw);
    const bf16x8 pf1 = ld8_bf(pw + 32);
#pragma unroll
    for (int d = 0; d < 4; ++d) {
      const unsigned short* vr = &vt_lds[d * 16 + (lane & 15)][(lane >> 4) * 8];
      o[d] = __builtin_amdgcn_mfma_f32_16x16x32_bf16(pf0, ld8_bf(vr), o[d], 0, 0, 0);
      o[d] = __builtin_amdgcn_mfma_f32_16x16x32_bf16(pf1, ld8_bf(vr + 32), o[d], 0, 0, 0);
    }
  }

  const int qg = qb0 + wave * 16 + (lane >> 4) * 4;
  const int oc = lane & 15;
#pragma unroll
  for (int r = 0; r < 4; ++r) {
    const float inv = 1.0f / l_r[r];
    unsigned short* orow = Ow + bbase + (size_t)(qg + r) * DM;
#pragma unroll
    for (int d = 0; d < 4; ++d) orow[d * 16 + oc] = f2bf(o[d][r] * inv);
  }
}

extern "C" void kernel_launch(void* const* d_in, const int* in_sizes, int n_in,
                              void* d_out, int out_size, void* d_ws, size_t ws_size,
                              hipStream_t stream) {
  const float* x_q  = (const float*)d_in[0];  // fp32 [4,2048,1024]
  const float* x_kv = (const float*)d_in[1];
  const float* Wq   = (const float*)d_in[2];  // fp32 [1024,1024]
  const float* Wk   = (const float*)d_in[3];
  const float* Wv   = (const float*)d_in[4];
  const float* Wo   = (const float*)d_in[5];
  float* out = (float*)d_out;                 // fp32 [4,2048,1024]

  // d_out doubles as early scratch (33.6 MB); final GEMM reads only from ws.
  unsigned short* scr  = (unsigned short*)d_out;
  unsigned short* Sx   = scr;                          // 8.4M u16 (x bf16 slot)
  unsigned short* Wk_b = scr + (size_t)MROWS * DM;     // 1M u16 each
  unsigned short* Wv_b = Wk_b + (size_t)DM * DM;
  unsigned short* Wq_b = Wv_b + (size_t)DM * DM;

  unsigned short* qb   = (unsigned short*)d_ws;        // 8.4M u16
  unsigned short* kb   = qb + (size_t)MROWS * DM;
  unsigned short* vb   = kb + (size_t)MROWS * DM;
  unsigned short* Wo_b = vb + (size_t)MROWS * DM;      // 1M u16

  const int nW8 = DM * DM / 8;          // 131072 -> 512 blocks
  const int nX8 = MROWS * DM / 8;       // 1048576 -> 4096 blocks

  conv_f32_bf16<<<nW8 / 256, 256, 0, stream>>>(Wk, Wk_b, nW8);
  conv_f32_bf16<<<nW8 / 256, 256, 0, stream>>>(Wv, Wv_b, nW8);
  conv_f32_bf16<<<nW8 / 256, 256, 0, stream>>>(Wq, Wq_b, nW8);
  conv_f32_bf16<<<nW8 / 256, 256, 0, stream>>>(Wo, Wo_b, nW8);
  conv_f32_bf16<<<nX8 / 256, 256, 0, stream>>>(x_kv, Sx, nX8);

  dim3 gg(DM / 128, MROWS / 128);  // (8, 64)
  gemm128<unsigned short><<<gg, 256, 0, stream>>>(Sx, Wk_b, kb, MROWS, DM, DM);
  gemm128<unsigned short><<<gg, 256, 0, stream>>>(Sx, Wv_b, vb, MROWS, DM, DM);
  conv_f32_bf16<<<nX8 / 256, 256, 0, stream>>>(x_q, Sx, nX8);
  gemm128<unsigned short><<<gg, 256, 0, stream>>>(Sx, Wq_b, qb, MROWS, DM, DM);
  attn_flash<<<dim3(T_SEQ / 64, NH, BB), 256, 0, stream>>>(qb, kb, vb, qb);
  gemm128<float><<<gg, 256, 0, stream>>>(qb, Wo_b, out, MROWS, DM, DM);
}

// Round 7
// 420.335 us; speedup vs baseline: 6.5390x; 1.2228x over previous
//
#include <hip/hip_runtime.h>
#include <stdint.h>

#define T_SEQ 2048
#define NH 16
#define HD 64
#define DM 1024
#define BB 4
#define MROWS (BB * T_SEQ)   // 8192

typedef __attribute__((ext_vector_type(8))) __bf16 bf16x8;
typedef __attribute__((ext_vector_type(8))) unsigned short u16x8;
typedef __attribute__((ext_vector_type(4))) unsigned short u16x4;
typedef __attribute__((ext_vector_type(4))) float f32x4;

__device__ __forceinline__ unsigned short f2bf(float f) {
  unsigned int x = __float_as_uint(f);
  x = (x + 0x7fffu + ((x >> 16) & 1u)) >> 16;  // RNE
  return (unsigned short)x;
}

__device__ __forceinline__ bf16x8 ld8_f32(const float* __restrict__ p) {
  f32x4 a = *(const f32x4*)p;
  f32x4 b = *(const f32x4*)(p + 4);
  u16x8 u;
#pragma unroll
  for (int i = 0; i < 4; ++i) {
    u[i]     = f2bf(a[i]);
    u[i + 4] = f2bf(b[i]);
  }
  return __builtin_bit_cast(bf16x8, u);
}

__device__ __forceinline__ bf16x8 ld8_bf(const unsigned short* p) {
  return __builtin_bit_cast(bf16x8, *(const u16x8*)p);
}

// 8-aligned LDS read as two b64s (stride-68 layouts are not 16B-aligned)
__device__ __forceinline__ bf16x8 ld8_lds(const unsigned short* p) {
  u16x4 a = *(const u16x4*)p;
  u16x4 b = *(const u16x4*)(p + 4);
  return __builtin_bit_cast(bf16x8,
      __builtin_shufflevector(a, b, 0, 1, 2, 3, 4, 5, 6, 7));
}

__device__ __forceinline__ u16x4 lo4(u16x8 v) {
  return __builtin_shufflevector(v, v, 0, 1, 2, 3);
}
__device__ __forceinline__ u16x4 hi4(u16x8 v) {
  return __builtin_shufflevector(v, v, 4, 5, 6, 7);
}

__device__ __forceinline__ void gload_lds16(const unsigned short* g,
                                            unsigned short* l) {
  __builtin_amdgcn_global_load_lds(
      (const __attribute__((address_space(1))) unsigned int*)g,
      (__attribute__((address_space(3))) unsigned int*)l, 16, 0, 0);
}

// ---------------------------------------------------------------------------
// fp32 -> bf16 elementwise (8 elems/thread).
// ---------------------------------------------------------------------------
__global__ __launch_bounds__(256) void conv_f32_bf16(
    const float* __restrict__ src, unsigned short* __restrict__ dst, int n8) {
  const int i = blockIdx.x * 256 + threadIdx.x;
  if (i < n8)
    *(u16x8*)(dst + (size_t)i * 8) =
        __builtin_bit_cast(u16x8, ld8_f32(src + (size_t)i * 8));
}

// ---------------------------------------------------------------------------
// m97-style bf16 GEMM: C = A[M,K] @ B[N,K]^T. 128x128 tile, BK=32,
// global_load_lds width=16. MODE 0: bf16 row-major out. MODE 1: f32
// row-major out. MODE 2: bf16 out transposed to Vt[b][h][d][t] (b64-packed).
// ---------------------------------------------------------------------------
template <int MODE>
__global__ __launch_bounds__(256) void gemm128(
    const unsigned short* __restrict__ A, const unsigned short* __restrict__ B,
    void* __restrict__ Cv, int M, int N, int K) {
  __shared__ __align__(16) unsigned short As[128 * 32];
  __shared__ __align__(16) unsigned short Bs[128 * 32];

  const int t = threadIdx.x;
  const int lane = t & 63, wave = t >> 6;
  const int m0 = blockIdx.y * 128, n0 = blockIdx.x * 128;

  const int srow = t >> 2;
  const int scol = (t & 3) * 8;
  const unsigned short* ga0 = A + (size_t)(m0 + srow) * K + scol;
  const unsigned short* ga1 = A + (size_t)(m0 + 64 + srow) * K + scol;
  const unsigned short* gb0 = B + (size_t)(n0 + srow) * K + scol;
  const unsigned short* gb1 = B + (size_t)(n0 + 64 + srow) * K + scol;
  unsigned short* lA0 = &As[(wave * 16) * 32];
  unsigned short* lA1 = &As[(64 + wave * 16) * 32];
  unsigned short* lB0 = &Bs[(wave * 16) * 32];
  unsigned short* lB1 = &Bs[(64 + wave * 16) * 32];

  const int mw = (wave >> 1) * 64, nw = (wave & 1) * 64;
  const int fr = lane & 15, fq = (lane >> 4) * 8;

  f32x4 acc[4][4];
#pragma unroll
  for (int i = 0; i < 4; ++i)
#pragma unroll
    for (int j = 0; j < 4; ++j) acc[i][j] = (f32x4){0.f, 0.f, 0.f, 0.f};

  for (int k0 = 0; k0 < K; k0 += 32) {
    __syncthreads();
    gload_lds16(ga0 + k0, lA0);
    gload_lds16(ga1 + k0, lA1);
    gload_lds16(gb0 + k0, lB0);
    gload_lds16(gb1 + k0, lB1);
    __syncthreads();

    bf16x8 af[4], bfr[4];
#pragma unroll
    for (int i = 0; i < 4; ++i)
      af[i] = ld8_bf(&As[(mw + i * 16 + fr) * 32 + fq]);
#pragma unroll
    for (int j = 0; j < 4; ++j)
      bfr[j] = ld8_bf(&Bs[(nw + j * 16 + fr) * 32 + fq]);
#pragma unroll
    for (int i = 0; i < 4; ++i)
#pragma unroll
      for (int j = 0; j < 4; ++j)
        acc[i][j] = __builtin_amdgcn_mfma_f32_16x16x32_bf16(af[i], bfr[j],
                                                            acc[i][j], 0, 0, 0);
  }

  const int orow = (lane >> 4) * 4, ocol = lane & 15;
#pragma unroll
  for (int i = 0; i < 4; ++i)
#pragma unroll
    for (int j = 0; j < 4; ++j) {
      if constexpr (MODE == 2) {
        // transposed pack: m -> (b,t), n -> (h,d); 4 r values = consecutive t
        const int mb = m0 + mw + i * 16 + orow;
        const int n = n0 + nw + j * 16 + ocol;
        u16x4 pk;
#pragma unroll
        for (int r = 0; r < 4; ++r) pk[r] = f2bf(acc[i][j][r]);
        unsigned short* dst = (unsigned short*)Cv +
            ((size_t)((mb >> 11) * NH + (n >> 6)) * HD + (n & 63)) * T_SEQ +
            (mb & 2047);
        *(u16x4*)dst = pk;
      } else {
#pragma unroll
        for (int r = 0; r < 4; ++r) {
          const size_t idx = (size_t)(m0 + mw + i * 16 + orow + r) * N +
                             (n0 + nw + j * 16 + ocol);
          if constexpr (MODE == 1)
            ((float*)Cv)[idx] = acc[i][j][r];
          else
            ((unsigned short*)Cv)[idx] = f2bf(acc[i][j][r]);
        }
      }
    }
}

// ---------------------------------------------------------------------------
// MFMA flash attention v2 (causal). Block = 128 q-rows of one (b,h), 4 waves
// x 32 q. S^T formulation: S^T = K @ Q^T (A=K-frag, B=Q-frag) so softmax is
// column-wise (2 shuffles) and P packs as b64 along keys. V pre-transposed
// globally (Vt[b][h][d][t]). All LDS tiles stride 68 u16 (2-way banks, free);
// frag access via b64 pairs. Q/O alias (in-place) is block-local-safe.
// ---------------------------------------------------------------------------
#define ASTR 68

__global__ __launch_bounds__(256, 4) void attn_flash2(
    const unsigned short* Qw, const unsigned short* __restrict__ Kw,
    const unsigned short* __restrict__ Vt, unsigned short* Ow) {
  __shared__ __align__(16) unsigned short k_lds[64][ASTR];
  __shared__ __align__(16) unsigned short vt_lds[64][ASTR];
  __shared__ __align__(16) unsigned short p_lds[4][32][ASTR];
  __shared__ float alpha_lds[4][32];
  __shared__ float l_lds[4][32];

  const int tid = threadIdx.x, lane = tid & 63, wave = tid >> 6;
  const int c16 = lane & 15, quad = lane >> 4;
  const int b = blockIdx.z, h = blockIdx.y;
  const int qt = (int)gridDim.x - 1 - (int)blockIdx.x;  // heavy blocks first
  const int qb0 = qt * 128;
  const size_t rkbase = (size_t)b * T_SEQ * DM + (size_t)h * HD;
  const size_t vtbase = (size_t)(b * NH + h) * HD * T_SEQ;

  // Q B-frags (resident): B[n=q][k=d], q = qb0+wave*32+nf*16+c16, d=quad*8+kf*32
  const int q_lo = qb0 + wave * 32;
  bf16x8 qf[2][2];
#pragma unroll
  for (int nf = 0; nf < 2; ++nf) {
    const unsigned short* qp =
        Qw + rkbase + (size_t)(q_lo + nf * 16 + c16) * DM + quad * 8;
    qf[nf][0] = ld8_bf(qp);
    qf[nf][1] = ld8_bf(qp + 32);
  }

  f32x4 o[2][4];
#pragma unroll
  for (int nf = 0; nf < 2; ++nf)
#pragma unroll
    for (int j = 0; j < 4; ++j) o[nf][j] = (f32x4){0.f, 0.f, 0.f, 0.f};
  float m_r[2] = {-3.0e38f, -3.0e38f};
  float l_r[2] = {0.f, 0.f};

  const int srow = tid >> 2;          // 0..63 (key idx for K, d idx for Vt)
  const int scol = (tid & 3) * 16;    // 0/16/32/48
  const int ntiles = (qb0 + 191) >> 6;
  const int ntiles_w = (q_lo + 95) >> 6;

  for (int t = 0; t < ntiles; ++t) {
    const int kb0 = t * 64;
    __syncthreads();
    {
      const unsigned short* kp = Kw + rkbase + (size_t)(kb0 + srow) * DM + scol;
      u16x8 ka = *(const u16x8*)kp;
      u16x8 kc = *(const u16x8*)(kp + 8);
      const unsigned short* vp =
          Vt + vtbase + (size_t)srow * T_SEQ + kb0 + scol;
      u16x8 va = *(const u16x8*)vp;
      u16x8 vc = *(const u16x8*)(vp + 8);
      *(u16x4*)&k_lds[srow][scol]       = lo4(ka);
      *(u16x4*)&k_lds[srow][scol + 4]   = hi4(ka);
      *(u16x4*)&k_lds[srow][scol + 8]   = lo4(kc);
      *(u16x4*)&k_lds[srow][scol + 12]  = hi4(kc);
      *(u16x4*)&vt_lds[srow][scol]      = lo4(va);
      *(u16x4*)&vt_lds[srow][scol + 4]  = hi4(va);
      *(u16x4*)&vt_lds[srow][scol + 8]  = lo4(vc);
      *(u16x4*)&vt_lds[srow][scol + 12] = hi4(vc);
    }
    __syncthreads();
    if (t >= ntiles_w) continue;  // barrier-safe: both barriers above

    // ---- S^T = K @ Q^T : D[m=key][n=q] ----
    f32x4 s[4][2];
#pragma unroll
    for (int mf = 0; mf < 4; ++mf) {
      const unsigned short* kr = &k_lds[mf * 16 + c16][quad * 8];
      const bf16x8 k0 = ld8_lds(kr);
      const bf16x8 k1 = ld8_lds(kr + 32);
#pragma unroll
      for (int nf = 0; nf < 2; ++nf) {
        f32x4 a = {0.f, 0.f, 0.f, 0.f};
        a = __builtin_amdgcn_mfma_f32_16x16x32_bf16(k0, qf[nf][0], a, 0, 0, 0);
        a = __builtin_amdgcn_mfma_f32_16x16x32_bf16(k1, qf[nf][1], a, 0, 0, 0);
        s[mf][nf] = a;
      }
    }
    // scale + causal mask: key = kb0+mf*16+quad*4+r, q = q_lo+nf*16+c16
    if (kb0 + 63 > q_lo) {
#pragma unroll
      for (int mf = 0; mf < 4; ++mf) {
        const int key0 = kb0 + mf * 16 + quad * 4;
#pragma unroll
        for (int nf = 0; nf < 2; ++nf) {
          const int qg = q_lo + nf * 16 + c16;
#pragma unroll
          for (int r = 0; r < 4; ++r)
            s[mf][nf][r] =
                (key0 + r <= qg) ? s[mf][nf][r] * 0.125f : -3.0e38f;
        }
      }
    } else {
#pragma unroll
      for (int mf = 0; mf < 4; ++mf)
#pragma unroll
        for (int nf = 0; nf < 2; ++nf)
#pragma unroll
          for (int r = 0; r < 4; ++r) s[mf][nf][r] *= 0.125f;
    }

    // ---- online softmax (per q = column): local 16 + shfl 16,32 ----
#pragma unroll
    for (int nf = 0; nf < 2; ++nf) {
      float mx = -3.0e38f;
#pragma unroll
      for (int mf = 0; mf < 4; ++mf)
#pragma unroll
        for (int r = 0; r < 4; ++r) mx = fmaxf(mx, s[mf][nf][r]);
      mx = fmaxf(mx, __shfl_xor(mx, 16, 64));
      mx = fmaxf(mx, __shfl_xor(mx, 32, 64));
      const float m_new = fmaxf(m_r[nf], mx);
      const float al = __expf(m_r[nf] - m_new);
      m_r[nf] = m_new;
      float ps = 0.f;
#pragma unroll
      for (int mf = 0; mf < 4; ++mf) {
        u16x4 pk;
#pragma unroll
        for (int r = 0; r < 4; ++r) {
          const float e = __expf(s[mf][nf][r] - m_new);
          ps += e;
          pk[r] = f2bf(e);
        }
        *(u16x4*)&p_lds[wave][nf * 16 + c16][mf * 16 + quad * 4] = pk;
      }
      ps += __shfl_xor(ps, 16, 64);
      ps += __shfl_xor(ps, 32, 64);
      l_r[nf] = l_r[nf] * al + ps;
      if (quad == 0) alpha_lds[wave][nf * 16 + c16] = al;
    }
    __threadfence_block();  // drain this wave's LDS writes (p, alpha)

    // ---- rescale O (alpha indexed by row q in C-layout) ----
#pragma unroll
    for (int nf = 0; nf < 2; ++nf) {
      float alr[4];
#pragma unroll
      for (int r = 0; r < 4; ++r)
        alr[r] = alpha_lds[wave][nf * 16 + quad * 4 + r];
#pragma unroll
      for (int j = 0; j < 4; ++j)
#pragma unroll
        for (int r = 0; r < 4; ++r) o[nf][j][r] *= alr[r];
    }

    // ---- O += P @ V : D[m=q][n=d], A=P-frag, B=Vt-frag ----
    bf16x8 pf[2][2];
#pragma unroll
    for (int nf = 0; nf < 2; ++nf) {
      const unsigned short* pw = &p_lds[wave][nf * 16 + c16][quad * 8];
      pf[nf][0] = ld8_lds(pw);
      pf[nf][1] = ld8_lds(pw + 32);
    }
#pragma unroll
    for (int j = 0; j < 4; ++j) {
      const unsigned short* vr = &vt_lds[j * 16 + c16][quad * 8];
      const bf16x8 v0 = ld8_lds(vr);
      const bf16x8 v1 = ld8_lds(vr + 32);
#pragma unroll
      for (int nf = 0; nf < 2; ++nf) {
        o[nf][j] =
            __builtin_amdgcn_mfma_f32_16x16x32_bf16(pf[nf][0], v0, o[nf][j], 0, 0, 0);
        o[nf][j] =
            __builtin_amdgcn_mfma_f32_16x16x32_bf16(pf[nf][1], v1, o[nf][j], 0, 0, 0);
      }
    }
  }

  // ---- epilogue: O/l, C-layout scatter (q = row) ----
  if (quad == 0) {
    l_lds[wave][c16] = l_r[0];
    l_lds[wave][16 + c16] = l_r[1];
  }
  __threadfence_block();
#pragma unroll
  for (int nf = 0; nf < 2; ++nf)
#pragma unroll
    for (int r = 0; r < 4; ++r) {
      const int qg = q_lo + nf * 16 + quad * 4 + r;
      const float inv = 1.0f / l_lds[wave][nf * 16 + quad * 4 + r];
      unsigned short* orow = Ow + rkbase + (size_t)qg * DM;
#pragma unroll
      for (int j = 0; j < 4; ++j)
        orow[j * 16 + c16] = f2bf(o[nf][j][r] * inv);
    }
}

extern "C" void kernel_launch(void* const* d_in, const int* in_sizes, int n_in,
                              void* d_out, int out_size, void* d_ws, size_t ws_size,
                              hipStream_t stream) {
  const float* x_q  = (const float*)d_in[0];
  const float* x_kv = (const float*)d_in[1];
  const float* Wq   = (const float*)d_in[2];
  const float* Wk   = (const float*)d_in[3];
  const float* Wv   = (const float*)d_in[4];
  const float* Wo   = (const float*)d_in[5];
  float* out = (float*)d_out;

  // d_out doubles as early scratch; final GEMM reads only from ws.
  unsigned short* scr  = (unsigned short*)d_out;
  unsigned short* Sx   = scr;                          // x bf16 slot
  unsigned short* Wk_b = scr + (size_t)MROWS * DM;
  unsigned short* Wv_b = Wk_b + (size_t)DM * DM;
  unsigned short* Wq_b = Wv_b + (size_t)DM * DM;

  unsigned short* qb   = (unsigned short*)d_ws;
  unsigned short* kb   = qb + (size_t)MROWS * DM;
  unsigned short* vtb  = kb + (size_t)MROWS * DM;      // Vt[b][h][d][t]
  unsigned short* Wo_b = vtb + (size_t)MROWS * DM;

  const int nW8 = DM * DM / 8;
  const int nX8 = MROWS * DM / 8;

  conv_f32_bf16<<<nW8 / 256, 256, 0, stream>>>(Wk, Wk_b, nW8);
  conv_f32_bf16<<<nW8 / 256, 256, 0, stream>>>(Wv, Wv_b, nW8);
  conv_f32_bf16<<<nW8 / 256, 256, 0, stream>>>(Wq, Wq_b, nW8);
  conv_f32_bf16<<<nW8 / 256, 256, 0, stream>>>(Wo, Wo_b, nW8);
  conv_f32_bf16<<<nX8 / 256, 256, 0, stream>>>(x_kv, Sx, nX8);

  dim3 gg(DM / 128, MROWS / 128);  // (8, 64)
  gemm128<0><<<gg, 256, 0, stream>>>(Sx, Wk_b, kb, MROWS, DM, DM);
  gemm128<2><<<gg, 256, 0, stream>>>(Sx, Wv_b, vtb, MROWS, DM, DM);
  conv_f32_bf16<<<nX8 / 256, 256, 0, stream>>>(x_q, Sx, nX8);
  gemm128<0><<<gg, 256, 0, stream>>>(Sx, Wq_b, qb, MROWS, DM, DM);
  attn_flash2<<<dim3(T_SEQ / 128, NH, BB), 256, 0, stream>>>(qb, kb, vtb, qb);
  gemm128<1><<<gg, 256, 0, stream>>>(qb, Wo_b, out, MROWS, DM, DM);
}